// Round 1
// baseline (707.194 us; speedup 1.0000x reference)
//
#include <hip/hip_runtime.h>

// Sparse MoE: T=4096 tokens, d=1024, E=8 experts, top-2, ffn=4096.
// Sparse path: route -> compact per-expert row lists (2T rows total) ->
// bf16 MFMA grouped GEMM1 (gelu) -> GEMM2 (scaled atomic scatter-add).
// ws usage ~201 MB: x_bf16 (8MB), w1t/w2t transposed bf16 (64MB each), h (64MB).

#define TOKENS 4096
#define DMODEL 1024
#define NEXP   8
#define DFF    4096
#define NROWS  (2*TOKENS)

typedef __bf16 bf16_t;
typedef __bf16 bf16x8 __attribute__((ext_vector_type(8)));
typedef __bf16 bf16x4 __attribute__((ext_vector_type(4)));
typedef float  f32x4  __attribute__((ext_vector_type(4)));

__device__ __forceinline__ void gl_lds16(const void* g, void* l) {
    // async global->LDS, 16B per lane; LDS dst = wave-uniform base + lane*16
    __builtin_amdgcn_global_load_lds(
        (const __attribute__((address_space(1))) void*)g,
        (__attribute__((address_space(3))) void*)l, 16, 0, 0);
}

// ---------------- router: logits, softmax, top-2, counts ----------------
__global__ __launch_bounds__(64) void router_k(
    const float* __restrict__ x, const float* __restrict__ rw,
    const float* __restrict__ rb, int* __restrict__ cnt,
    int* __restrict__ tok_e, int* __restrict__ tok_pos,
    float* __restrict__ tok_w, float* __restrict__ probs)
{
    int t = blockIdx.x;
    int lane = threadIdx.x;
    const float* xr = x + (size_t)t * DMODEL;
    float s[NEXP];
#pragma unroll
    for (int e = 0; e < NEXP; e++) s[e] = 0.f;
    for (int i = lane; i < DMODEL; i += 64) {
        float xv = xr[i];
        const float* wr = rw + (size_t)i * NEXP;
#pragma unroll
        for (int e = 0; e < NEXP; e++) s[e] += xv * wr[e];
    }
#pragma unroll
    for (int e = 0; e < NEXP; e++) {
#pragma unroll
        for (int o = 32; o > 0; o >>= 1) s[e] += __shfl_down(s[e], o, 64);
    }
    if (lane == 0) {
        float mx = -1e30f;
#pragma unroll
        for (int e = 0; e < NEXP; e++) { s[e] += rb[e]; mx = fmaxf(mx, s[e]); }
        float den = 0.f;
#pragma unroll
        for (int e = 0; e < NEXP; e++) { s[e] = expf(s[e] - mx); den += s[e]; }
        float inv = 1.f / den;
#pragma unroll
        for (int e = 0; e < NEXP; e++) { s[e] *= inv; probs[t * NEXP + e] = s[e]; }
        int e0 = 0;
#pragma unroll
        for (int e = 1; e < NEXP; e++) if (s[e] > s[e0]) e0 = e;
        int e1 = (e0 == 0) ? 1 : 0;
#pragma unroll
        for (int e = 0; e < NEXP; e++) if (e != e0 && s[e] > s[e1]) e1 = e;
        float sw = s[e0] + s[e1];
        int p0 = atomicAdd(&cnt[e0], 1);
        int p1 = atomicAdd(&cnt[e1], 1);
        tok_e[2 * t] = e0;       tok_e[2 * t + 1] = e1;
        tok_pos[2 * t] = p0;     tok_pos[2 * t + 1] = p1;
        tok_w[2 * t] = s[e0] / sw; tok_w[2 * t + 1] = s[e1] / sw;
    }
}

__global__ void offsets_k(const int* __restrict__ cnt, int* __restrict__ off)
{
    if (threadIdx.x == 0) {
        int a = 0;
        for (int e = 0; e < NEXP; e++) { off[e] = a; a += cnt[e]; }
        off[NEXP] = a;
    }
}

__global__ void scatter_k(const int* __restrict__ tok_e, const int* __restrict__ tok_pos,
                          const float* __restrict__ tok_w, const int* __restrict__ off,
                          int* __restrict__ rows_tok, float* __restrict__ roww)
{
    int i = blockIdx.x * blockDim.x + threadIdx.x;
    if (i < 2 * TOKENS) {
        int e = tok_e[i];
        int g = off[e] + tok_pos[i];
        rows_tok[g] = i >> 1;
        roww[g] = tok_w[i];
    }
}

// ---------------- fp32 -> bf16 convert (x) ----------------
__global__ __launch_bounds__(256) void convx_k(const float4* __restrict__ in,
                                               bf16x4* __restrict__ o, int n4)
{
    int i = blockIdx.x * blockDim.x + threadIdx.x;
    if (i < n4) {
        float4 v = in[i];
        bf16x4 r = { (bf16_t)v.x, (bf16_t)v.y, (bf16_t)v.z, (bf16_t)v.w };
        o[i] = r;
    }
}

// ---------------- transpose+convert: [E][K][N] f32 -> [E][N][K] bf16 ----------------
__global__ __launch_bounds__(256) void transconv_k(const float* __restrict__ in,
                                                   bf16_t* __restrict__ o, int K, int N)
{
    __shared__ float tile[32][33];
    int e = blockIdx.z;
    int n0 = blockIdx.x * 32, k0 = blockIdx.y * 32;
    int tx = threadIdx.x & 31, ty = threadIdx.x >> 5;  // 32 x 8
    const float* src = in + ((size_t)e * K + k0) * N + n0;
#pragma unroll
    for (int r = 0; r < 32; r += 8) tile[ty + r][tx] = src[(size_t)(ty + r) * N + tx];
    __syncthreads();
    bf16_t* dst = o + ((size_t)e * N + n0) * K + k0;
#pragma unroll
    for (int r = 0; r < 32; r += 8) dst[(size_t)(ty + r) * K + tx] = (bf16_t)tile[tx][ty + r];
}

// ---------------- grouped NT-GEMM, 128x128 tile, BK=64 ----------------
// MODE 0: h[row][:] = gelu(gather(x) @ w1 + b1)   (KDIM=1024, N=4096)
// MODE 1: out[tok][:] += w * (h @ w2 + b2)        (KDIM=4096, N=1024)
template<int KDIM, int MODE>
__global__ __launch_bounds__(256, 2) void ffn_gemm_k(
    const bf16_t* __restrict__ A, const bf16_t* __restrict__ Bt,
    const float* __restrict__ bias,
    const int* __restrict__ cnt, const int* __restrict__ off,
    const int* __restrict__ rows_tok, const float* __restrict__ roww,
    bf16_t* __restrict__ hbuf, float* __restrict__ out, int N)
{
    int e = blockIdx.z;
    int M = cnt[e];
    int m0 = blockIdx.y * 128;
    if (m0 >= M) return;
    int n0 = blockIdx.x * 128;
    int base = off[e];

    __shared__ __align__(16) bf16_t lA[128 * 64];
    __shared__ __align__(16) bf16_t lB[128 * 64];

    int tid = threadIdx.x;
    int wave = tid >> 6;
    int lane = tid & 63;
    // staging: each (wave,inst) fills one 1KB LDS chunk = 8 rows of 128B.
    // XOR swizzle: dst 16B-slot p of row r holds k-chunk p^(r&7).
    int sc = (lane & 7) ^ (lane >> 3);   // source k-chunk for this lane's dst slot

    const bf16_t* aRow[4];
    const bf16_t* bRow[4];
#pragma unroll
    for (int i = 0; i < 4; i++) {
        int r = (wave * 4 + i) * 8 + (lane >> 3);  // tile row 0..127
        int gr = m0 + r; if (gr > M - 1) gr = M - 1;
        if (MODE == 0) {
            int tok = rows_tok[base + gr];
            aRow[i] = A + (size_t)tok * KDIM;
        } else {
            aRow[i] = A + (size_t)(base + gr) * KDIM;
        }
        bRow[i] = Bt + ((size_t)e * N + n0 + r) * KDIM;  // same r pattern for B cols
    }

    f32x4 acc[4][4];
    f32x4 zero = { 0.f, 0.f, 0.f, 0.f };
#pragma unroll
    for (int i = 0; i < 4; i++)
#pragma unroll
        for (int j = 0; j < 4; j++) acc[i][j] = zero;

    int wrow = wave >> 1, wcol = wave & 1;

#pragma unroll 1
    for (int kk = 0; kk < KDIM / 64; ++kk) {
        int koff = kk * 64 + sc * 8;
#pragma unroll
        for (int i = 0; i < 4; i++) {
            gl_lds16(aRow[i] + koff, &lA[(wave * 4 + i) * 512]);
            gl_lds16(bRow[i] + koff, &lB[(wave * 4 + i) * 512]);
        }
        __syncthreads();
#pragma unroll
        for (int ks = 0; ks < 2; ++ks) {
            bf16x8 af[4], bfr[4];
#pragma unroll
            for (int mt = 0; mt < 4; mt++) {
                int r = wrow * 64 + mt * 16 + (lane & 15);
                int ch = (ks * 4 + (lane >> 4)) ^ (r & 7);
                af[mt] = *(const bf16x8*)&lA[r * 64 + ch * 8];
            }
#pragma unroll
            for (int nt = 0; nt < 4; nt++) {
                int c = wcol * 64 + nt * 16 + (lane & 15);
                int ch = (ks * 4 + (lane >> 4)) ^ (c & 7);
                bfr[nt] = *(const bf16x8*)&lB[c * 64 + ch * 8];
            }
#pragma unroll
            for (int mt = 0; mt < 4; mt++)
#pragma unroll
                for (int nt = 0; nt < 4; nt++)
                    acc[mt][nt] = __builtin_amdgcn_mfma_f32_16x16x32_bf16(
                        af[mt], bfr[nt], acc[mt][nt], 0, 0, 0);
        }
        __syncthreads();
    }

    // epilogue. C/D map: col = lane&15, row = (lane>>4)*4 + reg  [m89/m91]
    float bv[4];
#pragma unroll
    for (int nt = 0; nt < 4; nt++)
        bv[nt] = bias[(size_t)e * N + n0 + wcol * 64 + nt * 16 + (lane & 15)];

#pragma unroll
    for (int mt = 0; mt < 4; mt++) {
#pragma unroll
        for (int q = 0; q < 4; q++) {
            int r = wrow * 64 + mt * 16 + (lane >> 4) * 4 + q;
            int gm = m0 + r;
            if (gm < M) {
                if (MODE == 0) {
                    size_t hrow = (size_t)(base + gm) * DFF;
#pragma unroll
                    for (int nt = 0; nt < 4; nt++) {
                        float v = acc[mt][nt][q] + bv[nt];
                        v = 0.5f * v * (1.f + erff(v * 0.70710678118654752f));
                        int c = n0 + wcol * 64 + nt * 16 + (lane & 15);
                        hbuf[hrow + c] = (bf16_t)v;
                    }
                } else {
                    int g = base + gm;
                    int tok = rows_tok[g];
                    float wgt = roww[g];
                    size_t orow = (size_t)tok * DMODEL;
#pragma unroll
                    for (int nt = 0; nt < 4; nt++) {
                        float v = acc[mt][nt][q] + bv[nt];
                        int c = n0 + wcol * 64 + nt * 16 + (lane & 15);
                        atomicAdd(&out[orow + c], wgt * v);
                    }
                }
            }
        }
    }
}

// ---------------- aux loss: var(mean_probs, ddof=1) ----------------
__global__ __launch_bounds__(256) void aux_k(const float* __restrict__ probs,
                                             float* __restrict__ out_aux)
{
    __shared__ float red[256];
    __shared__ float mexp[NEXP];
    float s[NEXP];
#pragma unroll
    for (int e = 0; e < NEXP; e++) s[e] = 0.f;
    for (int t = threadIdx.x; t < TOKENS; t += 256) {
#pragma unroll
        for (int e = 0; e < NEXP; e++) s[e] += probs[t * NEXP + e];
    }
    for (int e = 0; e < NEXP; e++) {
        red[threadIdx.x] = s[e];
        __syncthreads();
        for (int st = 128; st > 0; st >>= 1) {
            if (threadIdx.x < st) red[threadIdx.x] += red[threadIdx.x + st];
            __syncthreads();
        }
        if (threadIdx.x == 0) mexp[e] = red[0] / (float)TOKENS;
        __syncthreads();
    }
    if (threadIdx.x == 0) {
        float mean = 0.f;
        for (int e = 0; e < NEXP; e++) mean += mexp[e];
        mean /= (float)NEXP;
        float v = 0.f;
        for (int e = 0; e < NEXP; e++) { float d = mexp[e] - mean; v += d * d; }
        out_aux[0] = v / (float)(NEXP - 1);
    }
}

extern "C" void kernel_launch(void* const* d_in, const int* in_sizes, int n_in,
                              void* d_out, int out_size, void* d_ws, size_t ws_size,
                              hipStream_t stream)
{
    const float* x  = (const float*)d_in[0];
    const float* rw = (const float*)d_in[1];
    const float* rb = (const float*)d_in[2];
    const float* w1 = (const float*)d_in[3];
    const float* b1 = (const float*)d_in[4];
    const float* w2 = (const float*)d_in[5];
    const float* b2 = (const float*)d_in[6];
    float* out = (float*)d_out;

    char* p = (char*)d_ws;
    auto alloc = [&](size_t b) { char* q = p; p += (b + 255) & ~(size_t)255; return q; };
    int*    cnt      = (int*)   alloc(NEXP * sizeof(int));
    int*    off      = (int*)   alloc((NEXP + 1) * sizeof(int));
    int*    tok_e    = (int*)   alloc(2 * TOKENS * sizeof(int));
    int*    tok_pos  = (int*)   alloc(2 * TOKENS * sizeof(int));
    float*  tok_w    = (float*) alloc(2 * TOKENS * sizeof(float));
    int*    rows_tok = (int*)   alloc(NROWS * sizeof(int));
    float*  roww     = (float*) alloc(NROWS * sizeof(float));
    float*  probs    = (float*) alloc((size_t)TOKENS * NEXP * sizeof(float));
    bf16_t* xb       = (bf16_t*)alloc((size_t)TOKENS * DMODEL * 2);
    bf16_t* w1t      = (bf16_t*)alloc((size_t)NEXP * DFF * DMODEL * 2);
    bf16_t* w2t      = (bf16_t*)alloc((size_t)NEXP * DMODEL * DFF * 2);
    bf16_t* hbuf     = (bf16_t*)alloc((size_t)NROWS * DFF * 2);

    hipMemsetAsync(cnt, 0, NEXP * sizeof(int), stream);
    hipMemsetAsync(d_out, 0, (size_t)out_size * sizeof(float), stream);

    router_k<<<TOKENS, 64, 0, stream>>>(x, rw, rb, cnt, tok_e, tok_pos, tok_w, probs);
    offsets_k<<<1, 64, 0, stream>>>(cnt, off);
    scatter_k<<<(2 * TOKENS + 255) / 256, 256, 0, stream>>>(tok_e, tok_pos, tok_w, off,
                                                            rows_tok, roww);
    convx_k<<<(TOKENS * DMODEL / 4 + 255) / 256, 256, 0, stream>>>(
        (const float4*)x, (bf16x4*)xb, TOKENS * DMODEL / 4);
    transconv_k<<<dim3(DFF / 32, DMODEL / 32, NEXP), 256, 0, stream>>>(w1, w1t, DMODEL, DFF);
    transconv_k<<<dim3(DMODEL / 32, DFF / 32, NEXP), 256, 0, stream>>>(w2, w2t, DFF, DMODEL);

    ffn_gemm_k<DMODEL, 0><<<dim3(DFF / 128, TOKENS / 128, NEXP), 256, 0, stream>>>(
        xb, w1t, b1, cnt, off, rows_tok, roww, hbuf, out, DFF);
    ffn_gemm_k<DFF, 1><<<dim3(DMODEL / 128, TOKENS / 128, NEXP), 256, 0, stream>>>(
        hbuf, w2t, b2, cnt, off, rows_tok, roww, hbuf, out, DMODEL);

    aux_k<<<1, 256, 0, stream>>>(probs, out + (size_t)TOKENS * DMODEL);
}